// Round 12
// baseline (1171.292 us; speedup 1.0000x reference)
//
#include <hip/hip_runtime.h>
#include <math.h>

// FNO2D: B=16, H=W=256, C_IN=C_OUT=2, WIDTH=64, MODES=16, NLAYERS=4
// Partial DFTs (32 kx rows x 16 ky cols). Batch in 2 chunks of CB=8.
// h stored as TWO bf16 planes (hi+lo, exact split of fp32).
// r11 + (a) k_dfth c-quarter split (grid 512, 2 blocks/CU),
//      (b) k_proj at 512 threads (halved per-wave phase work).

#define CB 8   // batch chunk size

typedef __attribute__((ext_vector_type(8))) __bf16 bf16x8;
typedef __attribute__((ext_vector_type(4))) float f32x4;

// ---- workspace layout (float offsets), per batch chunk ----
static const long long SZ_HC    = (long long)CB*256*256*64;  // 33,554,432 floats region
static const long long OFF_HLO_F= SZ_HC/2;                   // hi plane: ws[0..), lo plane as ushort
static const long long SZ_Y1C   = (long long)CB*16*256*64;   // 2,097,152 per plane
static const long long OFF_Y1RE = SZ_HC;
static const long long OFF_Y1IM = OFF_Y1RE + SZ_Y1C;
static const long long SZ_FTC   = (long long)CB*32*16*64;    // 262,144 per plane
static const long long OFF_FTRE = OFF_Y1RE + 2*SZ_Y1C;
static const long long OFF_FTIM = OFF_FTRE + SZ_FTC;
static const long long OFF_ORE  = OFF_FTRE + 2*SZ_FTC;
static const long long OFF_OIM  = OFF_FTRE + 3*SZ_FTC;
static const long long SZ_WT    = 4LL*32*16*64*64;           // 8,388,608 per plane
static const long long OFF_WTRE = OFF_FTRE + 4*SZ_FTC;
static const long long OFF_WTIM = OFF_WTRE + SZ_WT;
static const long long OFF_CWT  = OFF_WTIM + SZ_WT;          // legacy slot
static const long long OFF_FW   = OFF_CWT + 4LL*64*64;       // legacy slot
static const long long OFF_TW   = OFF_FW + 256LL*32;         // float2[256] (cos,sin)
static const long long OFF_TWA  = OFF_TW + 512;              // layer_out IDFT-W A frags (hi+lo)
static const long long OFF_CWB  = OFF_TWA + 8192;            // cw bf16 hi+lo
static const long long OFF_FWA  = OFF_CWB + 16384;           // dftw F A-frags hi+lo
static const long long OFF_P1T  = OFF_FWA + 8192;            // p1^T bf16 hi+lo
static const long long WS_FLOATS= OFF_P1T + 8192;            // ~212 MB

#define C2PI 0.0245436926061702596f
#define GELU(v) (0.5f*(v)*(1.0f + erff((v)*0.70710678118654752f)))

__device__ __forceinline__ void split2(float v, ushort& hi, ushort& lo) {
    unsigned u = __float_as_uint(v);
    hi = (ushort)(u >> 16);
    float fhi = __uint_as_float(u & 0xffff0000u);
    float r = v - fhi;
    lo = (ushort)(__float_as_uint(r) >> 16);
}

union U8 { ushort u[8]; uint4 v; };
union U4 { ushort u[4]; uint2 v; };

// ---- tables: TW, layer_out A-frags (TWA), dftw A-frags (FWA) ----
__global__ void k_init_tables(float* ws) {
    int t = threadIdx.x;
    float ang = (float)t * C2PI;
    float s, c;
    sincosf(ang, &s, &c);
    ((float2*)(ws + OFF_TW))[t] = make_float2(c, s);
    // TWA: layer_out A (rows w, K=kk): w = wt*16+(lane&15), kk = 8*(lane>>4)+j
    ushort* twh = (ushort*)(ws + OFF_TWA);
    ushort* twl = twh + 8192;
    int lidx = t & 63;
    int quarter = t >> 6;
    for (int wt = 0; wt < 16; wt++) {
        for (int jq = 0; jq < 2; jq++) {
            int j = quarter*2 + jq;
            int w = wt*16 + (lidx & 15);
            int kk = 8*(lidx >> 4) + j;
            int ky = kk >> 1;
            float a2 = (float)((ky * w) & 255) * C2PI;
            float ss, cc; sincosf(a2, &ss, &cc);
            float val = (kk & 1) ? -ss : cc;
            ushort hi, lo; split2(val, hi, lo);
            twh[(wt*64 + lidx)*8 + j] = hi;
            twl[(wt*64 + lidx)*8 + j] = lo;
        }
    }
    // FWA: dftw A (rows kk, K=w): kk = mt*16+(lane&15), w = ks*32+8*(lane>>4)+j
    ushort* fh = (ushort*)(ws + OFF_FWA);
    ushort* fl = fh + 8192;
    for (int n = t; n < 8192; n += 256) {
        int j = n & 7, ln = (n >> 3) & 63, ks = (n >> 9) & 7, mt2 = n >> 12;
        int kk = mt2*16 + (ln & 15);
        int w = ks*32 + 8*(ln >> 4) + j;
        int ky = kk >> 1;
        float a2 = (float)((ky * w) & 255) * C2PI;
        float ss, cc; sincosf(a2, &ss, &cc);
        float val = (kk & 1) ? -ss : cc;
        ushort hi, lo; split2(val, hi, lo);
        fh[n] = hi; fl[n] = lo;
    }
}

// ---- weight transpose: [l][i][o][x][ky] -> [l][kxi][ky][i][o] ----
__global__ __launch_bounds__(256) void k_wtrans(const float* w1r, const float* w1i,
                                                const float* w2r, const float* w2i,
                                                float* ws) {
    __shared__ float s_t[128*65];
    int t = threadIdx.x;
    int bid = blockIdx.x;                 // 2048 blocks
    int p    = bid & 1;
    int mh   = (bid >> 1) & 1;
    int tsel = (bid >> 2) & 1;
    int i    = (bid >> 3) & 63;
    int l    = bid >> 9;
    const float* src = tsel == 0 ? (p ? w1i : w1r) : (p ? w2i : w2r);
    const float* srcbase = src + ((long long)(l*64 + i)*64)*256;
    int msub = mh*128;
    for (int j = 0; j < 8; j++) {
        int n = j*256 + t;
        int o = n >> 5, mf4 = n & 31;
        float4 v = *(const float4*)(srcbase + o*256 + msub + mf4*4);
        int m0 = mf4*4;
        s_t[(m0+0)*65 + o] = v.x;
        s_t[(m0+1)*65 + o] = v.y;
        s_t[(m0+2)*65 + o] = v.z;
        s_t[(m0+3)*65 + o] = v.w;
    }
    __syncthreads();
    float* dst = ws + (p ? OFF_WTIM : OFF_WTRE);
    int o4 = t & 15, mq = t >> 4;
    for (int it = 0; it < 8; it++) {
        int ml = it*16 + mq;
        float4 w = make_float4(s_t[ml*65 + o4*4 + 0], s_t[ml*65 + o4*4 + 1],
                               s_t[ml*65 + o4*4 + 2], s_t[ml*65 + o4*4 + 3]);
        long long idx = ((long long)(l*512 + tsel*256 + msub + ml))*4096 + i*64 + o4*4;
        *(float4*)(dst + idx) = w;
    }
}

// ---- cw -> bf16 hi/lo planes [l][o][i] ----
__global__ void k_cwtrans(const float* cw, float* ws) {
    int gid = blockIdx.x * 256 + threadIdx.x;  // 16384
    ushort* ch = (ushort*)(ws + OFF_CWB);
    ushort* cl = ch + 16384;
    ushort hi, lo; split2(cw[gid], hi, lo);
    ch[gid] = hi; cl[gid] = lo;
}

// ---- p1 transpose -> bf16 hi/lo planes p1t[u(128)][i(64)] ----
__global__ void k_p1trans(const float* p1w, float* ws) {
    int gid = blockIdx.x * 256 + threadIdx.x;  // 8192
    int u = gid >> 6, i = gid & 63;
    ushort* ph = (ushort*)(ws + OFF_P1T);
    ushort hi, lo; split2(p1w[i*128 + u], hi, lo);
    ph[gid] = hi; ph[8192 + gid] = lo;
}

// ---- fused lift + chunk-initial DFT-W ----
__global__ __launch_bounds__(256) void k_liftdftw(const float* x, const float* lw,
                                                   const float* lb, float* ws, int bbase) {
    __shared__ ushort sBhi[64*128];
    __shared__ ushort sBlo[64*128];
    __shared__ float s_lw[192];
    int t = threadIdx.x;
    int bh = blockIdx.x;                  // CB*256
    int lane = t & 63, wid = t >> 6;
    int oc = lane & 15, g = lane >> 4;
    ushort* hH = (ushort*)ws;
    ushort* hL = (ushort*)(ws + OFF_HLO_F);
    const ushort* fh = (const ushort*)(ws + OFF_FWA);
    const ushort* fl = fh + 8192;
    if (t < 192) s_lw[t] = (t < 128) ? lw[t] : lb[t - 128];
    int mt = wid & 1, nt0 = wid >> 1;
    f32x4 acc0 = {0.f,0.f,0.f,0.f}, acc1 = {0.f,0.f,0.f,0.f};
    long long rowbase = (long long)bh * 16384;
    const float* xrow = x + ((long long)bbase*65536 + (long long)bh*256)*2;
    for (int half = 0; half < 2; half++) {
        __syncthreads();
        {
            int wl = t & 127;
            int w  = half*128 + wl;
            int cr = (t >> 7) * 32;
            float x0 = xrow[w*2], x1 = xrow[w*2 + 1];
            for (int cq = 0; cq < 4; cq++) {
                U8 hiv, lov;
                #pragma unroll
                for (int j = 0; j < 8; j++) {
                    int c = cr + cq*8 + j;
                    float v = x0*s_lw[c] + x1*s_lw[64 + c] + s_lw[128 + c];
                    split2(v, hiv.u[j], lov.u[j]);
                    int key = (((c & 7) ^ ((c >> 3) & 7)) << 3);
                    sBhi[c*128 + (wl ^ key)] = hiv.u[j];
                    sBlo[c*128 + (wl ^ key)] = lov.u[j];
                }
                long long ga = rowbase + (long long)w*64 + cr + cq*8;
                *(uint4*)&hH[ga] = hiv.v;
                *(uint4*)&hL[ga] = lov.v;
            }
        }
        __syncthreads();
        #pragma unroll
        for (int ksl = 0; ksl < 4; ksl++) {
            int gks = half*4 + ksl;
            bf16x8 Ah = *(const bf16x8*)&fh[((mt*8 + gks)*64 + lane)*8];
            bf16x8 Al = *(const bf16x8*)&fl[((mt*8 + gks)*64 + lane)*8];
            int wof = ksl*32 + 8*g;
            #pragma unroll
            for (int q = 0; q < 2; q++) {
                int c = (nt0 + q*2)*16 + oc;
                int key = (((c & 7) ^ ((c >> 3) & 7)) << 3);
                bf16x8 Bh = *(const bf16x8*)&sBhi[c*128 + (wof ^ key)];
                bf16x8 Bl = *(const bf16x8*)&sBlo[c*128 + (wof ^ key)];
                f32x4 a = q ? acc1 : acc0;
                a = __builtin_amdgcn_mfma_f32_16x16x32_bf16(Ah, Bh, a, 0,0,0);
                a = __builtin_amdgcn_mfma_f32_16x16x32_bf16(Al, Bh, a, 0,0,0);
                a = __builtin_amdgcn_mfma_f32_16x16x32_bf16(Ah, Bl, a, 0,0,0);
                if (q) acc1 = a; else acc0 = a;
            }
        }
    }
    int b = bh >> 8, hh = bh & 255;
    #pragma unroll
    for (int q = 0; q < 2; q++) {
        f32x4 a = q ? acc1 : acc0;
        int c = (nt0 + q*2)*16 + oc;
        #pragma unroll
        for (int r = 0; r < 4; r++) {
            int kk = mt*16 + 4*g + r;
            int ky = kk >> 1;
            long long addr = ((long long)(b*16 + ky)*256 + hh)*64 + c;
            ws[((kk & 1) ? OFF_Y1IM : OFF_Y1RE) + addr] = a[r];
        }
    }
}

// ---- DFT along H (fp32 VALU), c-quarter split: grid CB*64 ----
__global__ __launch_bounds__(256) void k_dfth(float* ws) {
    __shared__ __align__(16) float s_yre[64*16];
    __shared__ __align__(16) float s_yim[64*16];
    __shared__ __align__(16) float s_tw[512];
    int t = threadIdx.x;
    int bk = blockIdx.x;
    int cq = bk & 3;
    int ky = (bk >> 2) & 15;
    int b = bk >> 6;
    ((float2*)s_tw)[t] = ((const float2*)(ws + OFF_TW))[t];
    int kxi = t & 31;
    int cl = t >> 5;                      // 0..7, 2 c each
    int kxa = (kxi < 16) ? kxi : (224 + kxi);
    float accRe[2] = {0.f,0.f}, accIm[2] = {0.f,0.f};
    const float* yre = ws + OFF_Y1RE + (long long)(b*16 + ky)*(256*64);
    const float* yim = ws + OFF_Y1IM + (long long)(b*16 + ky)*(256*64);
    for (int chunk = 0; chunk < 4; chunk++) {
        __syncthreads();
        {
            int hl = t >> 2, c4 = t & 3;
            long long soff = (long long)(chunk*64 + hl)*64 + cq*16 + c4*4;
            ((float4*)s_yre)[hl*4 + c4] = *(const float4*)(yre + soff);
            ((float4*)s_yim)[hl*4 + c4] = *(const float4*)(yim + soff);
        }
        __syncthreads();
        for (int hl = 0; hl < 64; hl++) {
            int h = chunk*64 + hl;
            float2 tw = ((const float2*)s_tw)[(kxa*h) & 255];
            float2 yr = *(const float2*)&s_yre[hl*16 + 2*cl];
            float2 yi = *(const float2*)&s_yim[hl*16 + 2*cl];
            accRe[0] += yr.x*tw.x + yi.x*tw.y;
            accRe[1] += yr.y*tw.x + yi.y*tw.y;
            accIm[0] += yi.x*tw.x - yr.x*tw.y;
            accIm[1] += yi.y*tw.x - yr.y*tw.y;
        }
    }
    long long base = ((long long)((b*32 + kxi)*16 + ky))*64 + cq*16 + 2*cl;
    *(float2*)&ws[OFF_FTRE + base] = make_float2(accRe[0], accRe[1]);
    *(float2*)&ws[OFF_FTIM + base] = make_float2(accIm[0], accIm[1]);
}

// ---- mode mix ----
__global__ __launch_bounds__(256) void k_mix(float* ws, int l) {
    __shared__ __align__(16) float2 s_ft[CB*64];
    int t = threadIdx.x;
    int kk = blockIdx.x;
    int kxi = kk >> 4, ky = kk & 15;
    for (int j = 0; j < 2; j++) {
        int idx = j*256 + t;
        int i = idx & 63, b = idx >> 6;
        long long a = ((long long)(b*32 + kxi)*16 + ky)*64 + i;
        s_ft[b*64 + i] = make_float2(ws[OFF_FTRE + a], ws[OFF_FTIM + a]);
    }
    __syncthreads();
    int o = t & 63, bq = t >> 6;
    const float* wr = ws + OFF_WTRE + (((long long)l*32 + kxi)*16 + ky)*4096;
    const float* wi = ws + OFF_WTIM + (((long long)l*32 + kxi)*16 + ky)*4096;
    float accRe[2] = {0.f,0.f}, accIm[2] = {0.f,0.f};
    #pragma unroll 4
    for (int i = 0; i < 64; i++) {
        float wrv = wr[i*64 + o], wiv = wi[i*64 + o];
        #pragma unroll
        for (int j = 0; j < 2; j++) {
            float2 a = s_ft[(bq*2 + j)*64 + i];
            accRe[j] += a.x*wrv - a.y*wiv;
            accIm[j] += a.x*wiv + a.y*wrv;
        }
    }
    #pragma unroll
    for (int j = 0; j < 2; j++) {
        int b = bq*2 + j;
        long long a = ((long long)(b*32 + kxi)*16 + ky)*64 + o;
        ws[OFF_ORE + a] = accRe[j];
        ws[OFF_OIM + a] = accIm[j];
    }
}

// ---- fused layer (512 threads, 8 waves): IDFT-H(O)->B; conv+IDFT-W MFMA;
//      gelu -> h (+sT); DFT-W -> Y1 ----
__global__ __launch_bounds__(512) void k_layer_out(float* ws, const float* cb, int l, int do_dft) {
    __shared__ __align__(16) ushort sMem[16384];   // 32 KB union
    ushort* sBhi = sMem;          // conv-B 64*104
    ushort* sBlo = sMem + 6656;
    ushort* sAhi = sMem;          // h_old staging 128*64 (swizzled)
    ushort* sAlo = sMem + 8192;
    ushort* sThi = sMem;          // h_new transposed 64*128 (swizzled)
    ushort* sTlo = sMem + 8192;
    int t = threadIdx.x;
    int bh = blockIdx.x;
    int lane = t & 63, wid = t >> 6;          // wid 0..7
    int oc = lane & 15, g = lane >> 4;
    int b = bh >> 8, hh = bh & 255;
    ushort* hH = (ushort*)ws;
    ushort* hL = (ushort*)(ws + OFF_HLO_F);

    // ---- B: g part via fused IDFT-H from O (k=0..31); 2 cols per thread ----
    {
        int ky = t >> 5, o0 = (t & 31) * 2;
        const float* ore = ws + OFF_ORE;
        const float* oim = ws + OFF_OIM;
        const float2* twg = (const float2*)(ws + OFF_TW);
        float gr0=0,gr1=0, gi0=0,gi1=0;
        #pragma unroll 8
        for (int kxi = 0; kxi < 32; kxi++) {
            int kxa = (kxi < 16) ? kxi : (224 + kxi);
            float2 tw = twg[(kxa * hh) & 255];
            long long a = ((long long)((b*32 + kxi)*16 + ky))*64 + o0;
            float2 vr = *(const float2*)(ore + a);
            float2 vi = *(const float2*)(oim + a);
            gr0 += vr.x*tw.x - vi.x*tw.y;  gi0 += vr.x*tw.y + vi.x*tw.x;
            gr1 += vr.y*tw.x - vi.y*tw.y;  gi1 += vr.y*tw.y + vi.y*tw.x;
        }
        float scale = (ky == 0 ? 1.0f : 2.0f) * (1.0f/65536.0f);
        float grs[2] = {gr0,gr1}, gis[2] = {gi0,gi1};
        #pragma unroll
        for (int j = 0; j < 2; j++) {
            ushort h0,l0,h1,l1;
            split2(grs[j]*scale, h0, l0);
            split2(gis[j]*scale, h1, l1);
            int idx = (o0 + j)*104 + 2*ky;
            sBhi[idx] = h0; sBhi[idx+1] = h1;
            sBlo[idx] = l0; sBlo[idx+1] = l1;
        }
    }
    // ---- B: cw part (k=32..95) ----
    {
        const ushort* ch = (const ushort*)(ws + OFF_CWB) + (long long)l*4096;
        const ushort* clo = (const ushort*)(ws + OFF_CWB) + 16384 + (long long)l*4096;
        int n = t;
        int o = n >> 3, i0 = (n & 7)*8;
        *(uint4*)&sBhi[o*104 + 32 + i0] = *(const uint4*)&ch[o*64 + i0];
        *(uint4*)&sBlo[o*104 + 32 + i0] = *(const uint4*)&clo[o*64 + i0];
    }
    __syncthreads();
    int o = (wid & 3)*16 + oc;
    int wtg = wid >> 2;
    bf16x8 B_h[3], B_l[3];
    #pragma unroll
    for (int s = 0; s < 3; s++) {
        int kb = 32*s + 8*g;
        B_h[s] = *(bf16x8*)&sBhi[o*104 + kb];
        B_l[s] = *(bf16x8*)&sBlo[o*104 + kb];
    }
    __syncthreads();
    float cbv = cb[o];
    const ushort* twh = (const ushort*)(ws + OFF_TWA);
    const ushort* twl = twh + 8192;
    const ushort* fh = (const ushort*)(ws + OFF_FWA);
    const ushort* fl = fh + 8192;
    long long rowbase = (long long)bh * 16384;
    int mtd = wid & 1, ntd = (wid >> 1) & 3;
    f32x4 accY = {0.f,0.f,0.f,0.f};
    int keyo = ((o & 7) ^ ((o >> 3) & 7)) << 3;

    for (int half = 0; half < 2; half++) {
        const ushort* srcH = hH + rowbase + half*8192;
        const ushort* srcL = hL + rowbase + half*8192;
        for (int n = t; n < 1024; n += 512) {
            int row = n >> 3, i0 = (n & 7)*8;
            int idx = row*64 + (i0 ^ ((row & 7) << 3));
            *(uint4*)&sAhi[idx] = *(const uint4*)&srcH[row*64 + i0];
            *(uint4*)&sAlo[idx] = *(const uint4*)&srcL[row*64 + i0];
        }
        __syncthreads();
        f32x4 acc[4];
        #pragma unroll
        for (int wt = 0; wt < 4; wt++) {
            int awt = wtg*4 + wt;
            int gwt = half*8 + awt;
            bf16x8 A0h = *(const bf16x8*)&twh[(gwt*64 + lane)*8];
            bf16x8 A0l = *(const bf16x8*)&twl[(gwt*64 + lane)*8];
            int row = awt*16 + oc;
            int base = row*64;
            int sw = (row & 7) << 3;
            bf16x8 A1h = *(bf16x8*)&sAhi[base + ((8*g) ^ sw)];
            bf16x8 A1l = *(bf16x8*)&sAlo[base + ((8*g) ^ sw)];
            bf16x8 A2h = *(bf16x8*)&sAhi[base + ((32 + 8*g) ^ sw)];
            bf16x8 A2l = *(bf16x8*)&sAlo[base + ((32 + 8*g) ^ sw)];
            f32x4 a = {0.f,0.f,0.f,0.f};
            a = __builtin_amdgcn_mfma_f32_16x16x32_bf16(A0h, B_h[0], a, 0,0,0);
            a = __builtin_amdgcn_mfma_f32_16x16x32_bf16(A0l, B_h[0], a, 0,0,0);
            a = __builtin_amdgcn_mfma_f32_16x16x32_bf16(A0h, B_l[0], a, 0,0,0);
            a = __builtin_amdgcn_mfma_f32_16x16x32_bf16(A1h, B_h[1], a, 0,0,0);
            a = __builtin_amdgcn_mfma_f32_16x16x32_bf16(A1l, B_h[1], a, 0,0,0);
            a = __builtin_amdgcn_mfma_f32_16x16x32_bf16(A1h, B_l[1], a, 0,0,0);
            a = __builtin_amdgcn_mfma_f32_16x16x32_bf16(A2h, B_h[2], a, 0,0,0);
            a = __builtin_amdgcn_mfma_f32_16x16x32_bf16(A2l, B_h[2], a, 0,0,0);
            a = __builtin_amdgcn_mfma_f32_16x16x32_bf16(A2h, B_l[2], a, 0,0,0);
            acc[wt] = a;
        }
        __syncthreads();
        #pragma unroll
        for (int wt = 0; wt < 4; wt++) {
            int awt = wtg*4 + wt;
            U4 hi4, lo4;
            #pragma unroll
            for (int r = 0; r < 4; r++) {
                float v = acc[wt][r] + cbv;
                float gv = GELU(v);
                split2(gv, hi4.u[r], lo4.u[r]);
                long long oaddr = rowbase + (long long)(half*128 + awt*16 + 4*g + r)*64 + o;
                hH[oaddr] = hi4.u[r];
                hL[oaddr] = lo4.u[r];
            }
            if (do_dft) {
                int wl0 = awt*16 + 4*g;
                int tidx = o*128 + (wl0 ^ keyo);
                *(uint2*)&sThi[tidx] = hi4.v;
                *(uint2*)&sTlo[tidx] = lo4.v;
            }
        }
        if (do_dft) {
            __syncthreads();
            #pragma unroll
            for (int ksl = 0; ksl < 4; ksl++) {
                int gks = half*4 + ksl;
                bf16x8 Ah = *(const bf16x8*)&fh[((mtd*8 + gks)*64 + lane)*8];
                bf16x8 Al = *(const bf16x8*)&fl[((mtd*8 + gks)*64 + lane)*8];
                int wof = ksl*32 + 8*g;
                int c = ntd*16 + oc;
                int key = (((c & 7) ^ ((c >> 3) & 7)) << 3);
                bf16x8 Bh = *(const bf16x8*)&sThi[c*128 + (wof ^ key)];
                bf16x8 Bl = *(const bf16x8*)&sTlo[c*128 + (wof ^ key)];
                accY = __builtin_amdgcn_mfma_f32_16x16x32_bf16(Ah, Bh, accY, 0,0,0);
                accY = __builtin_amdgcn_mfma_f32_16x16x32_bf16(Al, Bh, accY, 0,0,0);
                accY = __builtin_amdgcn_mfma_f32_16x16x32_bf16(Ah, Bl, accY, 0,0,0);
            }
        }
        __syncthreads();
    }
    if (do_dft) {
        int c = ntd*16 + oc;
        #pragma unroll
        for (int r = 0; r < 4; r++) {
            int kk = mtd*16 + 4*g + r;
            int ky = kk >> 1;
            long long addr = ((long long)(b*16 + ky)*256 + hh)*64 + c;
            ws[((kk & 1) ? OFF_Y1IM : OFF_Y1RE) + addr] = accY[r];
        }
    }
}

// ---- projection via MFMA (512 threads, 8 waves), conflict-free s_u ----
__global__ __launch_bounds__(512) void k_proj(float* ws, const float* p1b,
                                              const float* p2w, const float* p2b, float* out) {
    __shared__ ushort sAhi[64*64];
    __shared__ ushort sAlo[64*64];
    __shared__ float s_u[32*132];
    __shared__ float s_p2[256];
    int t = threadIdx.x;
    int bh = blockIdx.x;
    int lane = t & 63, wid = t >> 6;   // 0..7
    int oc = lane & 15, g = lane >> 4;
    if (t < 256) s_p2[t] = p2w[t];
    const ushort* hH = (const ushort*)ws;
    const ushort* hL = (const ushort*)(ws + OFF_HLO_F);
    const ushort* ph = (const ushort*)(ws + OFF_P1T);
    const ushort* pl = ph + 8192;
    bf16x8 Bh[2], Bl[2];
    int u = wid*16 + oc;
    float p1bv = p1b[u];
    #pragma unroll
    for (int ks = 0; ks < 2; ks++) {
        Bh[ks] = *(const bf16x8*)&ph[u*64 + ks*32 + 8*g];
        Bl[ks] = *(const bf16x8*)&pl[u*64 + ks*32 + 8*g];
    }
    float p2b0 = p2b[0], p2b1 = p2b[1];
    long long rowbase = (long long)bh * 16384;
    float* obase = out + (long long)bh * 512;
    int uoff = u + (u >> 5);
    for (int qt = 0; qt < 4; qt++) {
        __syncthreads();
        {
            int n = t;                     // 512 covers 64 rows x 8 i-chunks
            int row = n >> 3, i0 = (n & 7)*8;
            long long gidx = rowbase + (long long)(qt*64 + row)*64 + i0;
            int idx = row*64 + (i0 ^ ((row & 7) << 3));
            *(uint4*)&sAhi[idx] = *(const uint4*)&hH[gidx];
            *(uint4*)&sAlo[idx] = *(const uint4*)&hL[gidx];
        }
        __syncthreads();
        for (int sub = 0; sub < 2; sub++) {
            #pragma unroll
            for (int mth = 0; mth < 2; mth++) {
                int mt = sub*2 + mth;
                int row = mt*16 + oc;
                int base = row*64, sw = (row & 7) << 3;
                bf16x8 A0h = *(bf16x8*)&sAhi[base + ((8*g) ^ sw)];
                bf16x8 A0l = *(bf16x8*)&sAlo[base + ((8*g) ^ sw)];
                bf16x8 A1h = *(bf16x8*)&sAhi[base + ((32 + 8*g) ^ sw)];
                bf16x8 A1l = *(bf16x8*)&sAlo[base + ((32 + 8*g) ^ sw)];
                f32x4 a = {0.f,0.f,0.f,0.f};
                a = __builtin_amdgcn_mfma_f32_16x16x32_bf16(A0h, Bh[0], a, 0,0,0);
                a = __builtin_amdgcn_mfma_f32_16x16x32_bf16(A0l, Bh[0], a, 0,0,0);
                a = __builtin_amdgcn_mfma_f32_16x16x32_bf16(A0h, Bl[0], a, 0,0,0);
                a = __builtin_amdgcn_mfma_f32_16x16x32_bf16(A1h, Bh[1], a, 0,0,0);
                a = __builtin_amdgcn_mfma_f32_16x16x32_bf16(A1l, Bh[1], a, 0,0,0);
                a = __builtin_amdgcn_mfma_f32_16x16x32_bf16(A1h, Bl[1], a, 0,0,0);
                #pragma unroll
                for (int r = 0; r < 4; r++) {
                    float v = a[r] + p1bv;
                    s_u[(mth*16 + 4*g + r)*132 + uoff] = GELU(v);
                }
            }
            __syncthreads();
            if (t < 256) {
                int wl = t >> 3, co = (t >> 2) & 1, seg = t & 3;
                float s = 0.f;
                #pragma unroll
                for (int uu = 0; uu < 32; uu++)
                    s += s_u[wl*132 + seg*33 + uu] * s_p2[(seg*32 + uu)*2 + co];
                s += __shfl_xor(s, 1);
                s += __shfl_xor(s, 2);
                if (seg == 0)
                    obase[(qt*64 + sub*32 + wl)*2 + co] = s + (co ? p2b1 : p2b0);
            }
            __syncthreads();
        }
    }
}

extern "C" void kernel_launch(void* const* d_in, const int* in_sizes, int n_in,
                              void* d_out, int out_size, void* d_ws, size_t ws_size,
                              hipStream_t stream) {
    (void)in_sizes; (void)n_in; (void)out_size; (void)ws_size;
    const float* x   = (const float*)d_in[0];
    const float* lw  = (const float*)d_in[1];
    const float* lb  = (const float*)d_in[2];
    const float* w1r = (const float*)d_in[3];
    const float* w1i = (const float*)d_in[4];
    const float* w2r = (const float*)d_in[5];
    const float* w2i = (const float*)d_in[6];
    const float* cw  = (const float*)d_in[7];
    const float* cb  = (const float*)d_in[8];
    const float* p1w = (const float*)d_in[9];
    const float* p1b = (const float*)d_in[10];
    const float* p2w = (const float*)d_in[11];
    const float* p2b = (const float*)d_in[12];
    float* ws  = (float*)d_ws;
    float* out = (float*)d_out;

    k_init_tables<<<dim3(1), dim3(256), 0, stream>>>(ws);
    k_wtrans<<<dim3(2048), dim3(256), 0, stream>>>(w1r, w1i, w2r, w2i, ws);
    k_cwtrans<<<dim3(64), dim3(256), 0, stream>>>(cw, ws);
    k_p1trans<<<dim3(32), dim3(256), 0, stream>>>(p1w, ws);
    for (int chunk = 0; chunk < 16/CB; chunk++) {
        k_liftdftw<<<dim3(CB*256), dim3(256), 0, stream>>>(x, lw, lb, ws, chunk*CB);
        for (int l = 0; l < 4; l++) {
            k_dfth<<<dim3(CB*64), dim3(256), 0, stream>>>(ws);
            k_mix<<<dim3(512), dim3(256), 0, stream>>>(ws, l);
            k_layer_out<<<dim3(CB*256), dim3(512), 0, stream>>>(ws, cb + l*64, l, (l < 3) ? 1 : 0);
        }
        k_proj<<<dim3(CB*256), dim3(512), 0, stream>>>(ws, p1b, p2w, p2b,
                                                       out + (long long)chunk*CB*256*256*2);
    }
}